// Round 1
// baseline (567.005 us; speedup 1.0000x reference)
//
#include <hip/hip_runtime.h>

#define N_NODES 100000
#define N_EDGES 1600000
#define D_IN    128
#define D_OUT   64

// ---------------------------------------------------------------------------
// Kernel 1: out[node][f] = b[f]   (vectorized float4; 6.4M floats)
// ---------------------------------------------------------------------------
__global__ void init_bias_kernel(float* __restrict__ out, const float* __restrict__ b) {
    int i = blockIdx.x * blockDim.x + threadIdx.x;          // float4 index
    const int total4 = N_NODES * (D_OUT / 4);               // 1.6M
    if (i < total4) {
        int f4 = i & (D_OUT / 4 - 1);                       // 0..15
        const float4* b4 = reinterpret_cast<const float4*>(b);
        reinterpret_cast<float4*>(out)[i] = b4[f4];
    }
}

// ---------------------------------------------------------------------------
// Kernel 2: h = x @ W   ([100000,128] x [128,64])
// Block 256 threads = 16 nodes x 16 lane-groups; each thread computes 4
// consecutive output features of one node. W rows read as float4 (L1-resident:
// W is 32 KB). x read as float4, broadcast across the 16 lanes of a node.
// ---------------------------------------------------------------------------
__global__ void gemm_kernel(const float* __restrict__ x, const float* __restrict__ W,
                            float* __restrict__ h) {
    const int tid  = threadIdx.x;
    const int node = blockIdx.x * 16 + (tid >> 4);
    const int f0   = (tid & 15) * 4;
    if (node >= N_NODES) return;

    const float4* x4 = reinterpret_cast<const float4*>(x + (size_t)node * D_IN);
    float4 acc = make_float4(0.f, 0.f, 0.f, 0.f);

    #pragma unroll 4
    for (int kk = 0; kk < D_IN / 4; ++kk) {
        const float4 xv = x4[kk];
        const float4 w0 = *reinterpret_cast<const float4*>(W + (size_t)(4 * kk + 0) * D_OUT + f0);
        const float4 w1 = *reinterpret_cast<const float4*>(W + (size_t)(4 * kk + 1) * D_OUT + f0);
        const float4 w2 = *reinterpret_cast<const float4*>(W + (size_t)(4 * kk + 2) * D_OUT + f0);
        const float4 w3 = *reinterpret_cast<const float4*>(W + (size_t)(4 * kk + 3) * D_OUT + f0);
        acc.x += xv.x * w0.x + xv.y * w1.x + xv.z * w2.x + xv.w * w3.x;
        acc.y += xv.x * w0.y + xv.y * w1.y + xv.z * w2.y + xv.w * w3.y;
        acc.z += xv.x * w0.z + xv.y * w1.z + xv.z * w2.z + xv.w * w3.z;
        acc.w += xv.x * w0.w + xv.y * w1.w + xv.z * w2.w + xv.w * w3.w;
    }
    *reinterpret_cast<float4*>(h + (size_t)node * D_OUT + f0) = acc;
}

// ---------------------------------------------------------------------------
// Kernel 3: scatter-add. One wave (64 lanes) per edge: lane f handles feature
// f. Coalesced 256B read of h[src], coalesced 256B atomic row-add to out[dst].
// ---------------------------------------------------------------------------
__global__ void scatter_kernel(const float* __restrict__ h, const int* __restrict__ ei,
                               float* __restrict__ out) {
    const long long t = (long long)blockIdx.x * blockDim.x + threadIdx.x;
    const int e = (int)(t >> 6);
    const int f = (int)(t & 63);
    if (e < N_EDGES) {
        const int src = ei[e];
        const int dst = ei[N_EDGES + e];
        const float v = h[(size_t)src * D_OUT + f];
        atomicAdd(out + (size_t)dst * D_OUT + f, v);
    }
}

// ---------------------------------------------------------------------------
// Kernel 4: relu in place (float4)
// ---------------------------------------------------------------------------
__global__ void relu_kernel(float* __restrict__ out) {
    int i = blockIdx.x * blockDim.x + threadIdx.x;
    const int total4 = N_NODES * (D_OUT / 4);
    if (i < total4) {
        float4 v = reinterpret_cast<float4*>(out)[i];
        v.x = fmaxf(v.x, 0.f);
        v.y = fmaxf(v.y, 0.f);
        v.z = fmaxf(v.z, 0.f);
        v.w = fmaxf(v.w, 0.f);
        reinterpret_cast<float4*>(out)[i] = v;
    }
}

// ---------------------------------------------------------------------------
extern "C" void kernel_launch(void* const* d_in, const int* in_sizes, int n_in,
                              void* d_out, int out_size, void* d_ws, size_t ws_size,
                              hipStream_t stream) {
    const float* x  = (const float*)d_in[0];       // [100000,128]
    const int*   ei = (const int*)d_in[1];         // [2,1600000]
    const float* W  = (const float*)d_in[2];       // [128,64]
    const float* b  = (const float*)d_in[3];       // [64]
    float* out = (float*)d_out;                    // [100000,64]
    float* h   = (float*)d_ws;                     // scratch: 25.6 MB for x@W

    // 1) out = bias (broadcast)
    {
        const int total4 = N_NODES * (D_OUT / 4);
        init_bias_kernel<<<(total4 + 255) / 256, 256, 0, stream>>>(out, b);
    }
    // 2) h = x @ W
    {
        const int blocks = (N_NODES + 15) / 16;
        gemm_kernel<<<blocks, 256, 0, stream>>>(x, W, h);
    }
    // 3) out[dst] += h[src] over all edges (atomic)
    {
        const long long threads = (long long)N_EDGES * 64;
        const int blocks = (int)((threads + 255) / 256);
        scatter_kernel<<<blocks, 256, 0, stream>>>(h, ei, out);
    }
    // 4) out = relu(out)
    {
        const int total4 = N_NODES * (D_OUT / 4);
        relu_kernel<<<(total4 + 255) / 256, 256, 0, stream>>>(out);
    }
}

// Round 2
// 495.739 us; speedup vs baseline: 1.1438x; 1.1438x over previous
//
#include <hip/hip_runtime.h>

#define N_NODES 100000
#define N_EDGES 1600000
#define D_IN    128
#define D_OUT   64

#define SCAN_CHUNK 1024
#define NB ((N_NODES + SCAN_CHUNK - 1) / SCAN_CHUNK)   // 98 blocks

// ---------------------------------------------------------------------------
// h = x @ W   ([100000,128] x [128,64]); 16 nodes/block, thread = node x 4 feats
// ---------------------------------------------------------------------------
__global__ void gemm_kernel(const float* __restrict__ x, const float* __restrict__ W,
                            float* __restrict__ h) {
    const int tid  = threadIdx.x;
    const int node = blockIdx.x * 16 + (tid >> 4);
    const int f0   = (tid & 15) * 4;
    if (node >= N_NODES) return;

    const float4* x4 = reinterpret_cast<const float4*>(x + (size_t)node * D_IN);
    float4 acc = make_float4(0.f, 0.f, 0.f, 0.f);

    #pragma unroll 4
    for (int kk = 0; kk < D_IN / 4; ++kk) {
        const float4 xv = x4[kk];
        const float4 w0 = *reinterpret_cast<const float4*>(W + (size_t)(4 * kk + 0) * D_OUT + f0);
        const float4 w1 = *reinterpret_cast<const float4*>(W + (size_t)(4 * kk + 1) * D_OUT + f0);
        const float4 w2 = *reinterpret_cast<const float4*>(W + (size_t)(4 * kk + 2) * D_OUT + f0);
        const float4 w3 = *reinterpret_cast<const float4*>(W + (size_t)(4 * kk + 3) * D_OUT + f0);
        acc.x += xv.x * w0.x + xv.y * w1.x + xv.z * w2.x + xv.w * w3.x;
        acc.y += xv.x * w0.y + xv.y * w1.y + xv.z * w2.y + xv.w * w3.y;
        acc.z += xv.x * w0.z + xv.y * w1.z + xv.z * w2.z + xv.w * w3.z;
        acc.w += xv.x * w0.w + xv.y * w1.w + xv.z * w2.w + xv.w * w3.w;
    }
    *reinterpret_cast<float4*>(h + (size_t)node * D_OUT + f0) = acc;
}

// ---------------------------------------------------------------------------
// CSR build step 1: in-degree histogram (deg must be pre-zeroed)
// ---------------------------------------------------------------------------
__global__ void hist_kernel(const int* __restrict__ ei, int* __restrict__ deg) {
    int e = blockIdx.x * blockDim.x + threadIdx.x;
    if (e < N_EDGES) atomicAdd(&deg[ei[N_EDGES + e]], 1);
}

// ---------------------------------------------------------------------------
// CSR build step 2a: per-1024-chunk sums
// ---------------------------------------------------------------------------
__global__ void partsum_kernel(const int* __restrict__ deg, int* __restrict__ bsum) {
    __shared__ int lds[256];
    const int base = blockIdx.x * SCAN_CHUNK;
    int s = 0;
    #pragma unroll
    for (int t = 0; t < 4; ++t) {
        int i = base + threadIdx.x + t * 256;
        s += (i < N_NODES) ? deg[i] : 0;
    }
    lds[threadIdx.x] = s;
    __syncthreads();
    for (int off = 128; off > 0; off >>= 1) {
        if (threadIdx.x < off) lds[threadIdx.x] += lds[threadIdx.x + off];
        __syncthreads();
    }
    if (threadIdx.x == 0) bsum[blockIdx.x] = lds[0];
}

// ---------------------------------------------------------------------------
// CSR build step 2b: serial exclusive scan of the 98 chunk sums (tiny)
// ---------------------------------------------------------------------------
__global__ void scanb_kernel(const int* __restrict__ bsum, int* __restrict__ boff,
                             int* __restrict__ row_start) {
    if (blockIdx.x == 0 && threadIdx.x == 0) {
        int acc = 0;
        for (int i = 0; i < NB; ++i) { boff[i] = acc; acc += bsum[i]; }
        row_start[N_NODES] = acc;   // == N_EDGES
    }
}

// ---------------------------------------------------------------------------
// CSR build step 2c: per-chunk exclusive scan + chunk offset -> row_start, next
// ---------------------------------------------------------------------------
__global__ void scanwrite_kernel(const int* __restrict__ deg, const int* __restrict__ boff,
                                 int* __restrict__ row_start, int* __restrict__ next) {
    __shared__ int lds[256];
    const int base = blockIdx.x * SCAN_CHUNK;
    int v[4];
    int s = 0;
    #pragma unroll
    for (int t = 0; t < 4; ++t) {
        int i = base + threadIdx.x * 4 + t;
        v[t] = (i < N_NODES) ? deg[i] : 0;
        s += v[t];
    }
    lds[threadIdx.x] = s;
    __syncthreads();
    // Hillis-Steele inclusive scan over 256 thread-sums
    for (int off = 1; off < 256; off <<= 1) {
        int val = (threadIdx.x >= off) ? lds[threadIdx.x - off] : 0;
        __syncthreads();
        lds[threadIdx.x] += val;
        __syncthreads();
    }
    int excl = ((threadIdx.x == 0) ? 0 : lds[threadIdx.x - 1]) + boff[blockIdx.x];
    #pragma unroll
    for (int t = 0; t < 4; ++t) {
        int i = base + threadIdx.x * 4 + t;
        if (i < N_NODES) { row_start[i] = excl; next[i] = excl; }
        excl += v[t];
    }
}

// ---------------------------------------------------------------------------
// CSR build step 3: scatter edge src ids into their CSR slots
// ---------------------------------------------------------------------------
__global__ void fill_kernel(const int* __restrict__ ei, int* __restrict__ next,
                            int* __restrict__ col) {
    int e = blockIdx.x * blockDim.x + threadIdx.x;
    if (e < N_EDGES) {
        const int d = ei[N_EDGES + e];
        const int pos = atomicAdd(&next[d], 1);
        col[pos] = ei[e];
    }
}

// ---------------------------------------------------------------------------
// Pull-gather: wave per node, lane = feature. out = relu(sum h[src] + b)
// Cols prefetched 64-wide per wave, broadcast via __shfl so the 64 row loads
// per chunk are independent (memory-level parallelism).
// ---------------------------------------------------------------------------
__global__ void gather_kernel(const float* __restrict__ h, const int* __restrict__ row_start,
                              const int* __restrict__ col, const float* __restrict__ b,
                              float* __restrict__ out) {
    const int wave = threadIdx.x >> 6;
    const int lane = threadIdx.x & 63;
    const int n = blockIdx.x * 4 + wave;
    if (n >= N_NODES) return;
    const int start = row_start[n];
    const int end   = row_start[n + 1];
    const float bias = b[lane];
    float acc = 0.f;
    for (int j0 = start; j0 < end; j0 += 64) {
        const int cnt = min(64, end - j0);
        int s = (lane < cnt) ? col[j0 + lane] : 0;
        for (int t = 0; t < cnt; ++t) {
            const int sj = __shfl(s, t, 64);
            acc += h[(size_t)sj * D_OUT + lane];
        }
    }
    out[(size_t)n * D_OUT + lane] = fmaxf(acc + bias, 0.f);
}

// ---------------------------------------------------------------------------
// Fallback path (atomic scatter) if ws is too small for the CSR build
// ---------------------------------------------------------------------------
__global__ void init_bias_kernel(float* __restrict__ out, const float* __restrict__ b) {
    int i = blockIdx.x * blockDim.x + threadIdx.x;
    const int total4 = N_NODES * (D_OUT / 4);
    if (i < total4) {
        int f4 = i & (D_OUT / 4 - 1);
        reinterpret_cast<float4*>(out)[i] = reinterpret_cast<const float4*>(b)[f4];
    }
}

__global__ void scatter_kernel(const float* __restrict__ h, const int* __restrict__ ei,
                               float* __restrict__ out) {
    const long long t = (long long)blockIdx.x * blockDim.x + threadIdx.x;
    const int e = (int)(t >> 6);
    const int f = (int)(t & 63);
    if (e < N_EDGES) {
        const int src = ei[e];
        const int dst = ei[N_EDGES + e];
        atomicAdd(out + (size_t)dst * D_OUT + f, h[(size_t)src * D_OUT + f]);
    }
}

__global__ void relu_kernel(float* __restrict__ out) {
    int i = blockIdx.x * blockDim.x + threadIdx.x;
    const int total4 = N_NODES * (D_OUT / 4);
    if (i < total4) {
        float4 v = reinterpret_cast<float4*>(out)[i];
        v.x = fmaxf(v.x, 0.f); v.y = fmaxf(v.y, 0.f);
        v.z = fmaxf(v.z, 0.f); v.w = fmaxf(v.w, 0.f);
        reinterpret_cast<float4*>(out)[i] = v;
    }
}

// ---------------------------------------------------------------------------
extern "C" void kernel_launch(void* const* d_in, const int* in_sizes, int n_in,
                              void* d_out, int out_size, void* d_ws, size_t ws_size,
                              hipStream_t stream) {
    const float* x  = (const float*)d_in[0];
    const int*   ei = (const int*)d_in[1];
    const float* W  = (const float*)d_in[2];
    const float* b  = (const float*)d_in[3];
    float* out = (float*)d_out;
    char*  ws  = (char*)d_ws;

    // ws layout (256B-aligned regions)
    size_t off = 0;
    auto take = [&](size_t bytes) { size_t p = off; off = (off + bytes + 255) & ~255ULL; return p; };
    const size_t o_h    = take((size_t)N_NODES * D_OUT * sizeof(float));   // 25.6 MB
    const size_t o_deg  = take((size_t)N_NODES * sizeof(int));
    const size_t o_rows = take((size_t)(N_NODES + 1) * sizeof(int));
    const size_t o_next = take((size_t)N_NODES * sizeof(int));
    const size_t o_bsum = take((size_t)NB * sizeof(int));
    const size_t o_boff = take((size_t)NB * sizeof(int));
    const size_t o_col  = take((size_t)N_EDGES * sizeof(int));             // 6.4 MB
    const size_t needed = off;

    float* h = (float*)(ws + o_h);

    // h = x @ W (both paths)
    gemm_kernel<<<(N_NODES + 15) / 16, 256, 0, stream>>>(x, W, h);

    if (needed <= ws_size) {
        int* deg  = (int*)(ws + o_deg);
        int* rows = (int*)(ws + o_rows);
        int* next = (int*)(ws + o_next);
        int* bsum = (int*)(ws + o_bsum);
        int* boff = (int*)(ws + o_boff);
        int* col  = (int*)(ws + o_col);

        hipMemsetAsync(deg, 0, (size_t)N_NODES * sizeof(int), stream);
        hist_kernel<<<(N_EDGES + 255) / 256, 256, 0, stream>>>(ei, deg);
        partsum_kernel<<<NB, 256, 0, stream>>>(deg, bsum);
        scanb_kernel<<<1, 64, 0, stream>>>(bsum, boff, rows);
        scanwrite_kernel<<<NB, 256, 0, stream>>>(deg, boff, rows, next);
        fill_kernel<<<(N_EDGES + 255) / 256, 256, 0, stream>>>(ei, next, col);
        gather_kernel<<<(N_NODES + 3) / 4, 256, 0, stream>>>(h, rows, col, b, out);
    } else {
        // fallback: atomic scatter path
        const int total4 = N_NODES * (D_OUT / 4);
        init_bias_kernel<<<(total4 + 255) / 256, 256, 0, stream>>>(out, b);
        const long long threads = (long long)N_EDGES * 64;
        scatter_kernel<<<(int)((threads + 255) / 256), 256, 0, stream>>>(h, ei, out);
        relu_kernel<<<(total4 + 255) / 256, 256, 0, stream>>>(out);
    }
}

// Round 3
// 403.713 us; speedup vs baseline: 1.4045x; 1.2280x over previous
//
#include <hip/hip_runtime.h>

#define N_NODES 100000
#define N_EDGES 1600000
#define D_IN    128
#define D_OUT   64

#define SCAN_CHUNK 1024
#define NB ((N_NODES + SCAN_CHUNK - 1) / SCAN_CHUNK)   // 98 blocks

// ---------------------------------------------------------------------------
// h = x @ W. 128 nodes/block, 256 threads. W staged in LDS (32 KB).
// Thread = 2 nodes x 16 output features (4 float4 accumulators per node).
// ---------------------------------------------------------------------------
__global__ __launch_bounds__(256) void gemm_kernel(const float* __restrict__ x,
                                                   const float* __restrict__ W,
                                                   float* __restrict__ h) {
    __shared__ float Wl[D_IN * D_OUT];              // [k][f] row-major, 32 KB
    float4* Wl4 = reinterpret_cast<float4*>(Wl);
    {
        const float4* Wg4 = reinterpret_cast<const float4*>(W);
        #pragma unroll
        for (int i = 0; i < (D_IN * D_OUT / 4) / 256; ++i)  // 8 iters
            Wl4[threadIdx.x + i * 256] = Wg4[threadIdx.x + i * 256];
    }
    __syncthreads();

    const int t   = threadIdx.x;
    const int fg  = t & 3;                 // feature group: f16 = fg*16
    const int ng  = t >> 2;                // 0..63 node pair group
    const int n0  = blockIdx.x * 128 + ng * 2;
    const int n1  = n0 + 1;
    const bool v0 = (n0 < N_NODES), v1 = (n1 < N_NODES);

    const float4* xa = reinterpret_cast<const float4*>(x) + (size_t)n0 * (D_IN / 4);
    const float4* xb = reinterpret_cast<const float4*>(x) + (size_t)n1 * (D_IN / 4);

    float4 acc0[4], acc1[4];
    #pragma unroll
    for (int c = 0; c < 4; ++c) {
        acc0[c] = make_float4(0.f, 0.f, 0.f, 0.f);
        acc1[c] = make_float4(0.f, 0.f, 0.f, 0.f);
    }

    #pragma unroll 2
    for (int kk = 0; kk < D_IN / 4; ++kk) {
        const float4 xv0 = v0 ? xa[kk] : make_float4(0.f, 0.f, 0.f, 0.f);
        const float4 xv1 = v1 ? xb[kk] : make_float4(0.f, 0.f, 0.f, 0.f);
        const float xs0[4] = {xv0.x, xv0.y, xv0.z, xv0.w};
        const float xs1[4] = {xv1.x, xv1.y, xv1.z, xv1.w};
        #pragma unroll
        for (int r = 0; r < 4; ++r) {
            const int k = 4 * kk + r;
            const float a0 = xs0[r], a1 = xs1[r];
            #pragma unroll
            for (int c = 0; c < 4; ++c) {
                const float4 w = Wl4[k * 16 + fg * 4 + c];
                acc0[c].x += a0 * w.x; acc0[c].y += a0 * w.y;
                acc0[c].z += a0 * w.z; acc0[c].w += a0 * w.w;
                acc1[c].x += a1 * w.x; acc1[c].y += a1 * w.y;
                acc1[c].z += a1 * w.z; acc1[c].w += a1 * w.w;
            }
        }
    }

    float4* h4 = reinterpret_cast<float4*>(h);
    if (v0) {
        #pragma unroll
        for (int c = 0; c < 4; ++c) h4[(size_t)n0 * 16 + fg * 4 + c] = acc0[c];
    }
    if (v1) {
        #pragma unroll
        for (int c = 0; c < 4; ++c) h4[(size_t)n1 * 16 + fg * 4 + c] = acc1[c];
    }
}

// ---------------------------------------------------------------------------
// CSR build step 1: in-degree histogram (deg pre-zeroed)
// ---------------------------------------------------------------------------
__global__ void hist_kernel(const int* __restrict__ ei, int* __restrict__ deg) {
    int e = blockIdx.x * blockDim.x + threadIdx.x;
    if (e < N_EDGES) atomicAdd(&deg[ei[N_EDGES + e]], 1);
}

// ---------------------------------------------------------------------------
// CSR build step 2a: per-1024-chunk sums
// ---------------------------------------------------------------------------
__global__ void partsum_kernel(const int* __restrict__ deg, int* __restrict__ bsum) {
    __shared__ int lds[256];
    const int base = blockIdx.x * SCAN_CHUNK;
    int s = 0;
    #pragma unroll
    for (int t = 0; t < 4; ++t) {
        int i = base + threadIdx.x + t * 256;
        s += (i < N_NODES) ? deg[i] : 0;
    }
    lds[threadIdx.x] = s;
    __syncthreads();
    for (int off = 128; off > 0; off >>= 1) {
        if (threadIdx.x < off) lds[threadIdx.x] += lds[threadIdx.x + off];
        __syncthreads();
    }
    if (threadIdx.x == 0) bsum[blockIdx.x] = lds[0];
}

// ---------------------------------------------------------------------------
// CSR build step 2b: serial exclusive scan of chunk sums (tiny)
// ---------------------------------------------------------------------------
__global__ void scanb_kernel(const int* __restrict__ bsum, int* __restrict__ boff,
                             int* __restrict__ row_start) {
    if (blockIdx.x == 0 && threadIdx.x == 0) {
        int acc = 0;
        for (int i = 0; i < NB; ++i) { boff[i] = acc; acc += bsum[i]; }
        row_start[N_NODES] = acc;
    }
}

// ---------------------------------------------------------------------------
// CSR build step 2c: per-chunk exclusive scan -> row_start, next
// ---------------------------------------------------------------------------
__global__ void scanwrite_kernel(const int* __restrict__ deg, const int* __restrict__ boff,
                                 int* __restrict__ row_start, int* __restrict__ next) {
    __shared__ int lds[256];
    const int base = blockIdx.x * SCAN_CHUNK;
    int v[4];
    int s = 0;
    #pragma unroll
    for (int t = 0; t < 4; ++t) {
        int i = base + threadIdx.x * 4 + t;
        v[t] = (i < N_NODES) ? deg[i] : 0;
        s += v[t];
    }
    lds[threadIdx.x] = s;
    __syncthreads();
    for (int off = 1; off < 256; off <<= 1) {
        int val = (threadIdx.x >= off) ? lds[threadIdx.x - off] : 0;
        __syncthreads();
        lds[threadIdx.x] += val;
        __syncthreads();
    }
    int excl = ((threadIdx.x == 0) ? 0 : lds[threadIdx.x - 1]) + boff[blockIdx.x];
    #pragma unroll
    for (int t = 0; t < 4; ++t) {
        int i = base + threadIdx.x * 4 + t;
        if (i < N_NODES) { row_start[i] = excl; next[i] = excl; }
        excl += v[t];
    }
}

// ---------------------------------------------------------------------------
// CSR build step 3: scatter src ids into CSR slots. atomicExch instead of a
// plain store: scattered stores write back 64B lines (measured 105.7 MB HBM
// WRITE); atomics write through at payload granularity (4B) -> ~13 MB.
// ---------------------------------------------------------------------------
__global__ void fill_kernel(const int* __restrict__ ei, int* __restrict__ next,
                            int* __restrict__ col) {
    int e = blockIdx.x * blockDim.x + threadIdx.x;
    if (e < N_EDGES) {
        const int d = ei[N_EDGES + e];
        const int pos = atomicAdd(&next[d], 1);
        atomicExch(&col[pos], ei[e]);
    }
}

// ---------------------------------------------------------------------------
// Pull-gather: wave per node. lane = (edge-sub 0..3) x (float4-feat 0..15).
// One load instr covers 4 edges x 256B rows = 1KB. Unroll x2 (8 edges/iter).
// Final cross-lane reduce over edge-subs via shfl_xor; bias+relu fused.
// ---------------------------------------------------------------------------
__global__ __launch_bounds__(256) void gather_kernel(const float* __restrict__ h,
                                                     const int* __restrict__ rows,
                                                     const int* __restrict__ col,
                                                     const float* __restrict__ b,
                                                     float* __restrict__ out) {
    const int wave = threadIdx.x >> 6;
    const int lane = threadIdx.x & 63;
    const int n = blockIdx.x * 4 + wave;
    if (n >= N_NODES) return;
    const int sub = lane >> 4;          // edge slot within group of 4
    const int f4  = lane & 15;          // float4 index within 64-float row
    const int start = rows[n];
    const int end   = rows[n + 1];
    const float4* h4 = reinterpret_cast<const float4*>(h);

    float4 acc = make_float4(0.f, 0.f, 0.f, 0.f);
    int j = start + sub;
    for (; j + 4 < end; j += 8) {
        const int s0 = col[j];
        const int s1 = col[j + 4];
        const float4 a = h4[(size_t)s0 * 16 + f4];
        const float4 c = h4[(size_t)s1 * 16 + f4];
        acc.x += a.x + c.x; acc.y += a.y + c.y;
        acc.z += a.z + c.z; acc.w += a.w + c.w;
    }
    if (j < end) {
        const int s0 = col[j];
        const float4 a = h4[(size_t)s0 * 16 + f4];
        acc.x += a.x; acc.y += a.y; acc.z += a.z; acc.w += a.w;
    }

    // reduce across the 4 edge-subgroups (lanes with equal f4)
    #pragma unroll
    for (int m = 16; m <= 32; m <<= 1) {
        acc.x += __shfl_xor(acc.x, m, 64);
        acc.y += __shfl_xor(acc.y, m, 64);
        acc.z += __shfl_xor(acc.z, m, 64);
        acc.w += __shfl_xor(acc.w, m, 64);
    }

    if (sub == 0) {
        const float4 bv = reinterpret_cast<const float4*>(b)[f4];
        float4 r;
        r.x = fmaxf(acc.x + bv.x, 0.f);
        r.y = fmaxf(acc.y + bv.y, 0.f);
        r.z = fmaxf(acc.z + bv.z, 0.f);
        r.w = fmaxf(acc.w + bv.w, 0.f);
        reinterpret_cast<float4*>(out)[(size_t)n * 16 + f4] = r;
    }
}

// ---------------------------------------------------------------------------
// Fallback path (atomic scatter) if ws too small
// ---------------------------------------------------------------------------
__global__ void init_bias_kernel(float* __restrict__ out, const float* __restrict__ b) {
    int i = blockIdx.x * blockDim.x + threadIdx.x;
    const int total4 = N_NODES * (D_OUT / 4);
    if (i < total4) {
        int f4 = i & (D_OUT / 4 - 1);
        reinterpret_cast<float4*>(out)[i] = reinterpret_cast<const float4*>(b)[f4];
    }
}

__global__ void scatter_kernel(const float* __restrict__ h, const int* __restrict__ ei,
                               float* __restrict__ out) {
    const long long t = (long long)blockIdx.x * blockDim.x + threadIdx.x;
    const int e = (int)(t >> 6);
    const int f = (int)(t & 63);
    if (e < N_EDGES) {
        atomicAdd(out + (size_t)ei[N_EDGES + e] * D_OUT + f,
                  h[(size_t)ei[e] * D_OUT + f]);
    }
}

__global__ void relu_kernel(float* __restrict__ out) {
    int i = blockIdx.x * blockDim.x + threadIdx.x;
    const int total4 = N_NODES * (D_OUT / 4);
    if (i < total4) {
        float4 v = reinterpret_cast<float4*>(out)[i];
        v.x = fmaxf(v.x, 0.f); v.y = fmaxf(v.y, 0.f);
        v.z = fmaxf(v.z, 0.f); v.w = fmaxf(v.w, 0.f);
        reinterpret_cast<float4*>(out)[i] = v;
    }
}

// ---------------------------------------------------------------------------
extern "C" void kernel_launch(void* const* d_in, const int* in_sizes, int n_in,
                              void* d_out, int out_size, void* d_ws, size_t ws_size,
                              hipStream_t stream) {
    const float* x  = (const float*)d_in[0];
    const int*   ei = (const int*)d_in[1];
    const float* W  = (const float*)d_in[2];
    const float* b  = (const float*)d_in[3];
    float* out = (float*)d_out;
    char*  ws  = (char*)d_ws;

    size_t off = 0;
    auto take = [&](size_t bytes) { size_t p = off; off = (off + bytes + 255) & ~255ULL; return p; };
    const size_t o_h    = take((size_t)N_NODES * D_OUT * sizeof(float));
    const size_t o_deg  = take((size_t)N_NODES * sizeof(int));
    const size_t o_rows = take((size_t)(N_NODES + 1) * sizeof(int));
    const size_t o_next = take((size_t)N_NODES * sizeof(int));
    const size_t o_bsum = take((size_t)NB * sizeof(int));
    const size_t o_boff = take((size_t)NB * sizeof(int));
    const size_t o_col  = take((size_t)N_EDGES * sizeof(int));
    const size_t needed = off;

    float* h = (float*)(ws + o_h);

    gemm_kernel<<<(N_NODES + 127) / 128, 256, 0, stream>>>(x, W, h);

    if (needed <= ws_size) {
        int* deg  = (int*)(ws + o_deg);
        int* rows = (int*)(ws + o_rows);
        int* next = (int*)(ws + o_next);
        int* bsum = (int*)(ws + o_bsum);
        int* boff = (int*)(ws + o_boff);
        int* col  = (int*)(ws + o_col);

        hipMemsetAsync(deg, 0, (size_t)N_NODES * sizeof(int), stream);
        hist_kernel<<<(N_EDGES + 255) / 256, 256, 0, stream>>>(ei, deg);
        partsum_kernel<<<NB, 256, 0, stream>>>(deg, bsum);
        scanb_kernel<<<1, 64, 0, stream>>>(bsum, boff, rows);
        scanwrite_kernel<<<NB, 256, 0, stream>>>(deg, boff, rows, next);
        fill_kernel<<<(N_EDGES + 255) / 256, 256, 0, stream>>>(ei, next, col);
        gather_kernel<<<(N_NODES + 3) / 4, 256, 0, stream>>>(h, rows, col, b, out);
    } else {
        const int total4 = N_NODES * (D_OUT / 4);
        init_bias_kernel<<<(total4 + 255) / 256, 256, 0, stream>>>(out, b);
        const long long threads = (long long)N_EDGES * 64;
        scatter_kernel<<<(int)((threads + 255) / 256), 256, 0, stream>>>(h, ei, out);
        relu_kernel<<<(total4 + 255) / 256, 256, 0, stream>>>(out);
    }
}